// Round 6
// baseline (183.381 us; speedup 1.0000x reference)
//
#include <hip/hip_runtime.h>
#include <math.h>

// Problem constants (setup_inputs: bs=16, nq=550, nc=91, nt=48, group_num=11)
#define BS 16
#define NQ 550
#define NC 91
#define NT 48
#define GN 11
#define GQ 50                 // queries per group
#define NTOT (BS * NT)        // 768
#define NROW 48               // LSA rows (targets) after reference transpose
#define MCOL 50               // LSA cols (queries)
#define NPAIR (GN * NT)       // 528
#define NLSA (BS * GN)        // 176 LSA blocks

// ---------------- focal (class) cost: fast f32 (R4/R6-proven) ---------------
__device__ __forceinline__ float focal_cost_f32(float x) {
    float prob = 1.0f / (1.0f + __expf(-x));
    float q = 1.0f - prob;
    float lneg = __logf(q + 1e-8f);
    float lpos = __logf(prob + 1e-8f);
    float neg = 0.75f * (prob * prob) * (-lneg);
    float pos = 0.25f * (q * q) * (-lpos);
    return pos - neg;
}

// ---------------- one C element, f32 __f*_rn box math ------------------------
__device__ __forceinline__ float cost_element(
    const float* __restrict__ logits,
    const float* __restrict__ pboxes, const int* __restrict__ labels,
    const float* __restrict__ tboxes, int p, int t)
{
    const float* pb = pboxes + (long)p * 6;
    float pcx = pb[0], pcy = pb[1], pl = pb[2], pr = pb[3], ptt = pb[4], pbo = pb[5];
    const float* tb = tboxes + (long)t * 6;
    float tcx = tb[0], tcy = tb[1], tl = tb[2], tr = tb[3], ttt = tb[4], tbo = tb[5];

    float c3d = __fadd_rn(fabsf(__fsub_rn(pcx, tcx)), fabsf(__fsub_rn(pcy, tcy)));
    float cbb = __fadd_rn(
                  __fadd_rn(
                    __fadd_rn(fabsf(__fsub_rn(pl, tl)), fabsf(__fsub_rn(pr, tr))),
                    fabsf(__fsub_rn(ptt, ttt))),
                  fabsf(__fsub_rn(pbo, tbo)));

    float px1 = __fsub_rn(pcx, pl), py1 = __fsub_rn(pcy, ptt);
    float px2 = __fadd_rn(pcx, pr), py2 = __fadd_rn(pcy, pbo);
    float tx1 = __fsub_rn(tcx, tl), ty1 = __fsub_rn(tcy, ttt);
    float tx2 = __fadd_rn(tcx, tr), ty2 = __fadd_rn(tcy, tbo);

    float area1 = __fmul_rn(__fsub_rn(px2, px1), __fsub_rn(py2, py1));
    float area2 = __fmul_rn(__fsub_rn(tx2, tx1), __fsub_rn(ty2, ty1));
    float ltx = fmaxf(px1, tx1), lty = fmaxf(py1, ty1);
    float rbx = fminf(px2, tx2), rby = fminf(py2, ty2);
    float wx = fmaxf(__fsub_rn(rbx, ltx), 0.0f);
    float wy = fmaxf(__fsub_rn(rby, lty), 0.0f);
    float inter = __fmul_rn(wx, wy);
    float uni = __fsub_rn(__fadd_rn(area1, area2), inter);
    float iou = __fdiv_rn(inter, uni);
    float ex1 = fminf(px1, tx1), ey1 = fminf(py1, ty1);
    float ex2 = fmaxf(px2, tx2), ey2 = fmaxf(py2, ty2);
    float ew = fmaxf(__fsub_rn(ex2, ex1), 0.0f);
    float eh = fmaxf(__fsub_rn(ey2, ey1), 0.0f);
    float earea = __fmul_rn(ew, eh);
    float giou = __fsub_rn(iou, __fdiv_rn(__fsub_rn(earea, uni), earea));
    float cgiou = -giou;

    float cclass = focal_cost_f32(logits[(long)p * NC + labels[t]]);

    float out = __fmul_rn(5.0f, cbb);
    out = __fadd_rn(out, __fmul_rn(10.0f, c3d));
    out = __fadd_rn(out, __fmul_rn(2.0f, cclass));
    out = __fadd_rn(out, __fmul_rn(2.0f, cgiou));
    return out;
}

// ---------------- cross-lane helpers ----------------------------------------
__device__ __forceinline__ double readlane_f64(double x, int l) {
    long long b = __double_as_longlong(x);
    int lo = __builtin_amdgcn_readlane((int)(b & 0xffffffffLL), l);
    int hi = __builtin_amdgcn_readlane((int)(b >> 32), l);
    return __longlong_as_double(((long long)hi << 32) | (unsigned int)lo);
}

// f32 key min-reduce across the wave (argmin lane finder, R2-proven). One
// update_dpp + one v_min_f32 per stage. f64->f32 RN conversion is monotone,
// so the lane set achieving the f32 key min always contains the true f64
// argmin lane; the exact f64 distance is recovered via readlane_f64 there.
template <int CTRL, int RM>
__device__ __forceinline__ float dpp_min_f32(float x) {
    int xi = __float_as_int(x);
    int t = __builtin_amdgcn_update_dpp(xi, xi, CTRL, RM, 0xf, false);
    return fminf(x, __int_as_float(t));
}

__device__ __forceinline__ float wave_min_key(float v) {
    float r = v;
    r = dpp_min_f32<0x111, 0xf>(r);  // row_shr:1
    r = dpp_min_f32<0x112, 0xf>(r);  // row_shr:2
    r = dpp_min_f32<0x114, 0xf>(r);  // row_shr:4
    r = dpp_min_f32<0x118, 0xf>(r);  // row_shr:8
    r = dpp_min_f32<0x142, 0xa>(r);  // row_bcast:15
    r = dpp_min_f32<0x143, 0xc>(r);  // row_bcast:31
    return __int_as_float(__builtin_amdgcn_readlane(__float_as_int(r), 63));
}

// ---------------- mega kernel: blocks [0,176) = LSA, rest = cost matrix -----
// R5: revert R3/R4's JV init (produced a different matching — abandoned).
// Back to the R2-verified reference trajectory (48 phases from zero duals),
// with the JV "dsum" transformation to remove ALL in-loop f64 dual updates:
//   - during a phase, v[j] of free columns and u of not-yet-visited rows are
//     never modified, so cur = (c - u_i0) - v_j uses phase-start values only;
//   - track mraw[j] = min over visits of (cur + dsum_at_visit); the argmin of
//     minv equals the argmin of mraw, and the new running shortest-path
//     distance is dsum <- mraw[j1] (an exact register copy, no arithmetic);
//   - per-column dual corrections are deferred to one write-back per phase:
//     v[j] -= (dsum_end - dsum_when_j_used), u[p[j]] += the same amount
//     (lane 0 carries u[i] with dused=0, receiving the full dsum_end).
//   - argmin key = cvt_f32(mraw - dsum) == cvt_f32(minv): bit-compatible with
//     R2's key up to 2^-52 reassociation (R2 tolerates 2^-24-level slop).
// In-loop work per iteration drops to: 1 f64 sub+add (m_in), cmp/sel, 1 f64
// sub + cvt (key), reduce, 3 readlanes, 1 speculative ds_read.
__global__ __launch_bounds__(256) void mega_kernel(
    const float* __restrict__ logits,
    const float* __restrict__ pboxes,
    const int*   __restrict__ labels,
    const float* __restrict__ tboxes,
    float*       __restrict__ C,
    float*       __restrict__ pi,
    float*       __restrict__ ti)
{
    if (blockIdx.x >= NLSA) {
        long idx = (long)(blockIdx.x - NLSA) * 256 + threadIdx.x;
        if (idx >= (long)BS * NQ * NTOT) return;
        int t = (int)(idx % NTOT);
        int p = (int)(idx / NTOT);
        C[idx] = cost_element(logits, pboxes, labels, tboxes, p, t);
        return;
    }

    // ---- LSA block ----
    const int blk = blockIdx.x;          // 0..175
    const int b = blk / GN, g = blk % GN;
    const int tid = threadIdx.x;

    __shared__ double lcost[NROW * MCOL];   // [row i][col j]

    // All 256 threads fill the 48x50 tile, then waves 1-3 exit.
    for (int k = tid; k < NROW * MCOL; k += 256) {
        int i = k % NROW, j = k / NROW;
        float cf = cost_element(logits, pboxes, labels, tboxes,
                                b * NQ + g * GQ + j, b * NT + i);
        lcost[i * MCOL + j] = (double)cf;
    }
    __syncthreads();
    if (tid >= 64) return;

    const int lane = tid;
    const bool incol = (lane >= 1 && lane <= MCOL);
    const int cidx = incol ? lane - 1 : 0;
    const double INF = __builtin_inf();
    const float INFF = __builtin_inff();

    int    pcol_l = 0;    // p[lane]   (0 = unassigned)
    double urow_l = 0.0;  // u[p[lane]]
    double v_l    = 0.0;  // v[lane]
    int    way_l  = 0;

    for (int i = 1; i <= NROW; ++i) {
        if (lane == 0) { pcol_l = i; urow_l = 0.0; }  // p[0]=i, u[i]=0

        double mraw_l  = INF;   // minv[j] + dsum_at_insert (shifted slack)
        bool   used_l  = false;
        double dused_l = 0.0;   // dsum when this column became used
        double dsum    = 0.0;   // running shortest-path distance (wave-uniform)
        int    j0 = 0;
        double cdu = lcost[(i - 1) * MCOL + cidx];   // c[i-1][j] - u[i], u[i]=0

        for (int guard = 0; guard <= MCOL + 1; ++guard) {
            bool newly = (lane == j0) && !used_l;
            dused_l = newly ? dsum : dused_l;
            used_l  = used_l || (lane == j0);
            bool freel = incol && !used_l;

            // shifted slack: (cur) + dsum, cur = (c - u_i0) - v_j (phase-start v)
            double m_in = (cdu - v_l) + dsum;
            bool upd   = freel && (m_in < mraw_l);
            mraw_l = upd ? m_in : mraw_l;
            way_l  = upd ? j0  : way_l;

            // key == cvt_f32(minv) as in R2 (minv = mraw - dsum)
            float kf = freel ? __double2float_rn(mraw_l - dsum) : INFF;

            float kmin = wave_min_key(kf);
            unsigned long long mm = __ballot(kf == kmin);
            int j1 = (int)__builtin_ctzll(mm);        // lowest lane = np.argmin

            int    i0n    = __builtin_amdgcn_readlane(pcol_l, j1);
            double dsum_n = readlane_f64(mraw_l, j1); // exact new distance
            double u_nx   = readlane_f64(urow_l, j1); // phase-start u[p[j1]]

            // speculative next-row load, clamped (result unused on break)
            int r_next = (i0n > 0) ? (i0n - 1) : 0;
            double cd_next = lcost[r_next * MCOL + cidx];

            dsum = dsum_n;
            j0 = j1;
            if (i0n == 0) break;
            cdu = cd_next - u_nx;
        }

        // deferred dual write-back: total delta since each column became used
        {
            double adj = dsum - dused_l;
            v_l    = used_l ? v_l - adj    : v_l;
            urow_l = used_l ? urow_l + adj : urow_l;
        }

        // augment back-walk: p[j]=p[way[j]], moving urow with pcol
        int j = j0;
        while (j != 0) {
            int wj    = __builtin_amdgcn_readlane(way_l, j);
            int pr    = __builtin_amdgcn_readlane(pcol_l, wj);
            double ur = readlane_f64(urow_l, wj);
            if (lane == j) { pcol_l = pr; urow_l = ur; }
            j = wj;
        }
    }

    // Extraction: ascending query (column) order == reference order.
    unsigned long long asg = __ballot(incol && pcol_l != 0);
    if (incol && pcol_l != 0) {
        int k = __popcll(asg & ((1ull << lane) - 1));
        float* pib = pi + ((long)b * NPAIR + (long)g * NT);
        float* tib = ti + ((long)b * NPAIR + (long)g * NT);
        pib[k] = (float)(g * GQ + cidx);
        tib[k] = (float)(pcol_l - 1);
    }
}

extern "C" void kernel_launch(void* const* d_in, const int* in_sizes, int n_in,
                              void* d_out, int out_size, void* d_ws, size_t ws_size,
                              hipStream_t stream) {
    const float* logits = (const float*)d_in[0];   // [16,550,91] f32
    const float* pboxes = (const float*)d_in[1];   // [16,550,6] f32
    const int*   labels = (const int*)d_in[2];     // [16,48] i32
    const float* tboxes = (const float*)d_in[3];   // [16,48,6] f32

    float* out = (float*)d_out;
    float* C  = out;                               // 16*550*768
    float* pi = out + (long)BS * NQ * NTOT;
    float* ti = pi + (long)BS * NPAIR;

    long total = (long)BS * NQ * NTOT;
    int cost_blocks = (int)((total + 255) / 256);
    int mega_blocks = NLSA + cost_blocks;

    mega_kernel<<<mega_blocks, 256, 0, stream>>>(
        logits, pboxes, labels, tboxes, C, pi, ti);
}

// Round 7
// 182.405 us; speedup vs baseline: 1.0054x; 1.0054x over previous
//
#include <hip/hip_runtime.h>
#include <math.h>

// Problem constants (setup_inputs: bs=16, nq=550, nc=91, nt=48, group_num=11)
#define BS 16
#define NQ 550
#define NC 91
#define NT 48
#define GN 11
#define GQ 50                 // queries per group
#define NTOT (BS * NT)        // 768
#define NROW 48               // LSA rows (targets) after reference transpose
#define MCOL 50               // LSA cols (queries)
#define NPAIR (GN * NT)       // 528
#define NLSA (BS * GN)        // 176 LSA blocks

typedef float f32x32 __attribute__((ext_vector_type(32)));
typedef float f32x16 __attribute__((ext_vector_type(16)));

// ---------------- focal (class) cost: fast f32 (R4/R6-proven) ---------------
__device__ __forceinline__ float focal_cost_f32(float x) {
    float prob = 1.0f / (1.0f + __expf(-x));
    float q = 1.0f - prob;
    float lneg = __logf(q + 1e-8f);
    float lpos = __logf(prob + 1e-8f);
    float neg = 0.75f * (prob * prob) * (-lneg);
    float pos = 0.25f * (q * q) * (-lpos);
    return pos - neg;
}

// ---------------- one C element, f32 __f*_rn box math ------------------------
__device__ __forceinline__ float cost_element(
    const float* __restrict__ logits,
    const float* __restrict__ pboxes, const int* __restrict__ labels,
    const float* __restrict__ tboxes, int p, int t)
{
    const float* pb = pboxes + (long)p * 6;
    float pcx = pb[0], pcy = pb[1], pl = pb[2], pr = pb[3], ptt = pb[4], pbo = pb[5];
    const float* tb = tboxes + (long)t * 6;
    float tcx = tb[0], tcy = tb[1], tl = tb[2], tr = tb[3], ttt = tb[4], tbo = tb[5];

    float c3d = __fadd_rn(fabsf(__fsub_rn(pcx, tcx)), fabsf(__fsub_rn(pcy, tcy)));
    float cbb = __fadd_rn(
                  __fadd_rn(
                    __fadd_rn(fabsf(__fsub_rn(pl, tl)), fabsf(__fsub_rn(pr, tr))),
                    fabsf(__fsub_rn(ptt, ttt))),
                  fabsf(__fsub_rn(pbo, tbo)));

    float px1 = __fsub_rn(pcx, pl), py1 = __fsub_rn(pcy, ptt);
    float px2 = __fadd_rn(pcx, pr), py2 = __fadd_rn(pcy, pbo);
    float tx1 = __fsub_rn(tcx, tl), ty1 = __fsub_rn(tcy, ttt);
    float tx2 = __fadd_rn(tcx, tr), ty2 = __fadd_rn(tcy, tbo);

    float area1 = __fmul_rn(__fsub_rn(px2, px1), __fsub_rn(py2, py1));
    float area2 = __fmul_rn(__fsub_rn(tx2, tx1), __fsub_rn(ty2, ty1));
    float ltx = fmaxf(px1, tx1), lty = fmaxf(py1, ty1);
    float rbx = fminf(px2, tx2), rby = fminf(py2, ty2);
    float wx = fmaxf(__fsub_rn(rbx, ltx), 0.0f);
    float wy = fmaxf(__fsub_rn(rby, lty), 0.0f);
    float inter = __fmul_rn(wx, wy);
    float uni = __fsub_rn(__fadd_rn(area1, area2), inter);
    float iou = __fdiv_rn(inter, uni);
    float ex1 = fminf(px1, tx1), ey1 = fminf(py1, ty1);
    float ex2 = fmaxf(px2, tx2), ey2 = fmaxf(py2, ty2);
    float ew = fmaxf(__fsub_rn(ex2, ex1), 0.0f);
    float eh = fmaxf(__fsub_rn(ey2, ey1), 0.0f);
    float earea = __fmul_rn(ew, eh);
    float giou = __fsub_rn(iou, __fdiv_rn(__fsub_rn(earea, uni), earea));
    float cgiou = -giou;

    float cclass = focal_cost_f32(logits[(long)p * NC + labels[t]]);

    float out = __fmul_rn(5.0f, cbb);
    out = __fadd_rn(out, __fmul_rn(10.0f, c3d));
    out = __fadd_rn(out, __fmul_rn(2.0f, cclass));
    out = __fadd_rn(out, __fmul_rn(2.0f, cgiou));
    return out;
}

// ---------------- cross-lane helpers ----------------------------------------
__device__ __forceinline__ double readlane_f64(double x, int l) {
    long long b = __double_as_longlong(x);
    int lo = __builtin_amdgcn_readlane((int)(b & 0xffffffffLL), l);
    int hi = __builtin_amdgcn_readlane((int)(b >> 32), l);
    return __longlong_as_double(((long long)hi << 32) | (unsigned int)lo);
}

// f32 key min-reduce across the wave (argmin lane finder, R2-proven). One
// update_dpp + one v_min_f32 per stage. f64->f32 RN conversion is monotone,
// so the lane set achieving the f32 key min always contains the true f64
// argmin lane; the exact f64 value is recovered via readlane_f64 there.
template <int CTRL, int RM>
__device__ __forceinline__ float dpp_min_f32(float x) {
    int xi = __float_as_int(x);
    int t = __builtin_amdgcn_update_dpp(xi, xi, CTRL, RM, 0xf, false);
    return fminf(x, __int_as_float(t));
}

__device__ __forceinline__ float wave_min_key(float v) {
    float r = v;
    r = dpp_min_f32<0x111, 0xf>(r);  // row_shr:1
    r = dpp_min_f32<0x112, 0xf>(r);  // row_shr:2
    r = dpp_min_f32<0x114, 0xf>(r);  // row_shr:4
    r = dpp_min_f32<0x118, 0xf>(r);  // row_shr:8
    r = dpp_min_f32<0x142, 0xa>(r);  // row_bcast:15
    r = dpp_min_f32<0x143, 0xc>(r);  // row_bcast:31
    return __int_as_float(__builtin_amdgcn_readlane(__float_as_int(r), 63));
}

// ---------------- mega kernel: blocks [0,176) = LSA, rest = cost matrix -----
// R7: revert R5's dsum transform (regressed: it moved work INTO the post-load
// critical path; R2's in-loop dual updates were already hidden in the
// ds_read shadow). Back to the R2-verified loop VERBATIM, with ONE change:
// the in-loop LDS row-gather (ds_read ~120 cy, the dominant chain term) is
// replaced by a per-lane REGISTER table of the lane's cost column (48 f32 in
// two ext-vectors, 32+16). The row index is wave-uniform (readlane -> SGPR),
// so the dynamic extractelement lowers to m0 + v_movrels_b32 (~10 cy), not
// scratch. Costs were always f64-promotions of f32 values, so (double)cf
// reproduces the old LDS f64 bit-exactly -> trajectory identical to R2.
__global__ __launch_bounds__(256) void mega_kernel(
    const float* __restrict__ logits,
    const float* __restrict__ pboxes,
    const int*   __restrict__ labels,
    const float* __restrict__ tboxes,
    float*       __restrict__ C,
    float*       __restrict__ pi,
    float*       __restrict__ ti)
{
    if (blockIdx.x >= NLSA) {
        long idx = (long)(blockIdx.x - NLSA) * 256 + threadIdx.x;
        if (idx >= (long)BS * NQ * NTOT) return;
        int t = (int)(idx % NTOT);
        int p = (int)(idx / NTOT);
        C[idx] = cost_element(logits, pboxes, labels, tboxes, p, t);
        return;
    }

    // ---- LSA block ----
    const int blk = blockIdx.x;          // 0..175
    const int b = blk / GN, g = blk % GN;
    const int tid = threadIdx.x;

    __shared__ float lcost[NROW * MCOL];   // [row i][col j], f32 staging

    // All 256 threads fill the 48x50 tile, then waves 1-3 exit.
    for (int k = tid; k < NROW * MCOL; k += 256) {
        int i = k % NROW, j = k / NROW;
        float cf = cost_element(logits, pboxes, labels, tboxes,
                                b * NQ + g * GQ + j, b * NT + i);
        lcost[i * MCOL + j] = cf;
    }
    __syncthreads();
    if (tid >= 64) return;

    const int lane = tid;
    const bool incol = (lane >= 1 && lane <= MCOL);
    const int cidx = incol ? lane - 1 : 0;
    const double INF = __builtin_inf();
    const float INFF = __builtin_inff();

    // ---- per-lane register table: this lane's cost column (48 rows) --------
    f32x32 t0;
    f32x16 t1;
    #pragma unroll
    for (int k = 0; k < 32; ++k) t0[k] = lcost[k * MCOL + cidx];
    #pragma unroll
    for (int k = 0; k < 16; ++k) t1[k] = lcost[(k + 32) * MCOL + cidx];

    int    pcol_l = 0;    // p[lane]   (0 = unassigned)
    double urow_l = 0.0;  // u[p[lane]]
    double v_l    = 0.0;  // v[lane]
    int    way_l  = 0;
    double minv_l = INF;
    float  kprev  = INFF; // f32 image of minv_l (monotone)
    bool   used_l = false;

    for (int i = 1; i <= NROW; ++i) {
        if (lane == 0) { pcol_l = i; urow_l = 0.0; }  // p[0]=i, u[i]=0
        minv_l = INF;
        kprev  = INFF;
        used_l = false;
        int j0 = 0;
        int i0 = i;            // p[j0], wave-uniform
        double u_i0 = 0.0;     // u[i0]

        // row (i0-1) cost from the register table (uniform index)
        int s0 = i0 - 1;
        float lo0 = t0[s0 & 31];
        float hi0 = t1[(s0 - 32) & 15];
        double cd = (double)((s0 < 32) ? lo0 : hi0);

        for (int guard = 0; guard <= MCOL + 1; ++guard) {
            used_l = used_l || (lane == j0);
            bool freel = incol && !used_l;

            double cur = (cd - u_i0) - v_l;           // (cost - u) - v, ref order
            bool upd   = freel && (cur < minv_l);
            minv_l = upd ? cur : minv_l;
            way_l  = upd ? j0  : way_l;

            // f32 key: exact image of updated minv for free lanes, +inf else.
            float kf = freel ? fminf(__double2float_rn(cur), kprev) : INFF;

            float kmin = wave_min_key(kf);
            unsigned long long mm = __ballot(kf == kmin);
            int j1 = (int)__builtin_ctzll(mm);        // lowest lane = np.argmin

            int    i0n   = __builtin_amdgcn_readlane(pcol_l, j1);
            double delta = readlane_f64(minv_l, j1);  // exact f64 min value
            double u_nx  = readlane_f64(urow_l, j1);

            // next-row cost from the register table (uniform index, clamped;
            // value unused when i0n==0 and we break)
            int s = i0n - 1;
            s = (s > 0) ? s : 0;
            float lo = t0[s & 31];
            float hi = t1[(s - 32) & 15];
            double cd_next = (double)((s < 32) ? lo : hi);

            urow_l = used_l ? urow_l + delta : urow_l;
            v_l    = used_l ? v_l - delta    : v_l;
            minv_l = freel  ? minv_l - delta : minv_l;
            kprev  = __double2float_rn(minv_l);

            j0 = j1;
            if (i0n == 0) break;
            i0   = i0n;
            u_i0 = u_nx;
            cd   = cd_next;
        }

        // augment back-walk: p[j]=p[way[j]], moving urow with pcol
        int j = j0;
        while (j != 0) {
            int wj    = __builtin_amdgcn_readlane(way_l, j);
            int pr    = __builtin_amdgcn_readlane(pcol_l, wj);
            double ur = readlane_f64(urow_l, wj);
            if (lane == j) { pcol_l = pr; urow_l = ur; }
            j = wj;
        }
    }

    // Extraction: ascending query (column) order == reference order.
    unsigned long long asg = __ballot(incol && pcol_l != 0);
    if (incol && pcol_l != 0) {
        int k = __popcll(asg & ((1ull << lane) - 1));
        float* pib = pi + ((long)b * NPAIR + (long)g * NT);
        float* tib = ti + ((long)b * NPAIR + (long)g * NT);
        pib[k] = (float)(g * GQ + cidx);
        tib[k] = (float)(pcol_l - 1);
    }
}

extern "C" void kernel_launch(void* const* d_in, const int* in_sizes, int n_in,
                              void* d_out, int out_size, void* d_ws, size_t ws_size,
                              hipStream_t stream) {
    const float* logits = (const float*)d_in[0];   // [16,550,91] f32
    const float* pboxes = (const float*)d_in[1];   // [16,550,6] f32
    const int*   labels = (const int*)d_in[2];     // [16,48] i32
    const float* tboxes = (const float*)d_in[3];   // [16,48,6] f32

    float* out = (float*)d_out;
    float* C  = out;                               // 16*550*768
    float* pi = out + (long)BS * NQ * NTOT;
    float* ti = pi + (long)BS * NPAIR;

    long total = (long)BS * NQ * NTOT;
    int cost_blocks = (int)((total + 255) / 256);
    int mega_blocks = NLSA + cost_blocks;

    mega_kernel<<<mega_blocks, 256, 0, stream>>>(
        logits, pboxes, labels, tboxes, C, pi, ti);
}

// Round 8
// 160.363 us; speedup vs baseline: 1.1435x; 1.1374x over previous
//
#include <hip/hip_runtime.h>
#include <math.h>

// Problem constants (setup_inputs: bs=16, nq=550, nc=91, nt=48, group_num=11)
#define BS 16
#define NQ 550
#define NC 91
#define NT 48
#define GN 11
#define GQ 50                 // queries per group
#define NTOT (BS * NT)        // 768
#define NROW 48               // LSA rows (targets) after reference transpose
#define MCOL 50               // LSA cols (queries)
#define NPAIR (GN * NT)       // 528
#define NLSA (BS * GN)        // 176 LSA blocks

// ---------------- focal (class) cost: fast f32 (R4/R6-proven) ---------------
__device__ __forceinline__ float focal_cost_f32(float x) {
    float prob = 1.0f / (1.0f + __expf(-x));
    float q = 1.0f - prob;
    float lneg = __logf(q + 1e-8f);
    float lpos = __logf(prob + 1e-8f);
    float neg = 0.75f * (prob * prob) * (-lneg);
    float pos = 0.25f * (q * q) * (-lpos);
    return pos - neg;
}

// ---------------- one C element, f32 __f*_rn box math ------------------------
__device__ __forceinline__ float cost_element(
    const float* __restrict__ logits,
    const float* __restrict__ pboxes, const int* __restrict__ labels,
    const float* __restrict__ tboxes, int p, int t)
{
    const float* pb = pboxes + (long)p * 6;
    float pcx = pb[0], pcy = pb[1], pl = pb[2], pr = pb[3], ptt = pb[4], pbo = pb[5];
    const float* tb = tboxes + (long)t * 6;
    float tcx = tb[0], tcy = tb[1], tl = tb[2], tr = tb[3], ttt = tb[4], tbo = tb[5];

    float c3d = __fadd_rn(fabsf(__fsub_rn(pcx, tcx)), fabsf(__fsub_rn(pcy, tcy)));
    float cbb = __fadd_rn(
                  __fadd_rn(
                    __fadd_rn(fabsf(__fsub_rn(pl, tl)), fabsf(__fsub_rn(pr, tr))),
                    fabsf(__fsub_rn(ptt, ttt))),
                  fabsf(__fsub_rn(pbo, tbo)));

    float px1 = __fsub_rn(pcx, pl), py1 = __fsub_rn(pcy, ptt);
    float px2 = __fadd_rn(pcx, pr), py2 = __fadd_rn(pcy, pbo);
    float tx1 = __fsub_rn(tcx, tl), ty1 = __fsub_rn(tcy, ttt);
    float tx2 = __fadd_rn(tcx, tr), ty2 = __fadd_rn(tcy, tbo);

    float area1 = __fmul_rn(__fsub_rn(px2, px1), __fsub_rn(py2, py1));
    float area2 = __fmul_rn(__fsub_rn(tx2, tx1), __fsub_rn(ty2, ty1));
    float ltx = fmaxf(px1, tx1), lty = fmaxf(py1, ty1);
    float rbx = fminf(px2, tx2), rby = fminf(py2, ty2);
    float wx = fmaxf(__fsub_rn(rbx, ltx), 0.0f);
    float wy = fmaxf(__fsub_rn(rby, lty), 0.0f);
    float inter = __fmul_rn(wx, wy);
    float uni = __fsub_rn(__fadd_rn(area1, area2), inter);
    float iou = __fdiv_rn(inter, uni);
    float ex1 = fminf(px1, tx1), ey1 = fminf(py1, ty1);
    float ex2 = fmaxf(px2, tx2), ey2 = fmaxf(py2, ty2);
    float ew = fmaxf(__fsub_rn(ex2, ex1), 0.0f);
    float eh = fmaxf(__fsub_rn(ey2, ey1), 0.0f);
    float earea = __fmul_rn(ew, eh);
    float giou = __fsub_rn(iou, __fdiv_rn(__fsub_rn(earea, uni), earea));
    float cgiou = -giou;

    float cclass = focal_cost_f32(logits[(long)p * NC + labels[t]]);

    float out = __fmul_rn(5.0f, cbb);
    out = __fadd_rn(out, __fmul_rn(10.0f, c3d));
    out = __fadd_rn(out, __fmul_rn(2.0f, cclass));
    out = __fadd_rn(out, __fmul_rn(2.0f, cgiou));
    return out;
}

// ---------------- cross-lane helpers ----------------------------------------
__device__ __forceinline__ double readlane_f64(double x, int l) {
    long long b = __double_as_longlong(x);
    int lo = __builtin_amdgcn_readlane((int)(b & 0xffffffffLL), l);
    int hi = __builtin_amdgcn_readlane((int)(b >> 32), l);
    return __longlong_as_double(((long long)hi << 32) | (unsigned int)lo);
}

// order-preserving f32 -> u32 map: a < b (float, no NaN) <=> fkey(a) < fkey(b)
// (+inf maps to 0xFF800000; negatives to ~bits). Bijective, so u32-key
// equality == f32 bit equality and the winner set matches R2's float compare
// (difference only at +0/-0 ties: measure-zero for this data).
__device__ __forceinline__ unsigned fkey_u32(float f) {
    unsigned b = __float_as_uint(f);
    return b ^ (unsigned)(((int)b >> 31) | 0x80000000);
}

// one within-row-of-16 DPP u32-min stage
template <int CTRL>
__device__ __forceinline__ unsigned dpp_min_u32(unsigned x) {
    unsigned t = (unsigned)__builtin_amdgcn_update_dpp((int)x, (int)x, CTRL, 0xf, 0xf, false);
    return (x < t) ? x : t;
}

// ---------------- mega kernel: blocks [0,176) = LSA, rest = cost matrix -----
// R8: back to the R2-verified 110-us loop (f64 LDS tile, exact f64 state,
// speculative next-row ds_read). ONE change, bit-identical by construction:
// the wave argmin. R2 used a 6-stage f32 DPP chain (4x row_shr + 2x
// row_bcast) + readlane63 + float ballot. R8 maps the same f32 key through
// an order-preserving u32 transform, runs only the 4 within-row stages
// (v_min_u32), pulls the 4 row minima (lanes 15/31/47/63) via readlane, and
// finishes on the SALU (3x s_min_u32). Ballot compares each lane's OWN u32
// key against the SGPR kmin; ctz = lowest lane = np.argmin. Same winner,
// same delta bits, same trajectory -> same output as R2; ~20-25 fewer
// serial cycles per inner iteration on the pre-load critical path.
__global__ __launch_bounds__(256) void mega_kernel(
    const float* __restrict__ logits,
    const float* __restrict__ pboxes,
    const int*   __restrict__ labels,
    const float* __restrict__ tboxes,
    float*       __restrict__ C,
    float*       __restrict__ pi,
    float*       __restrict__ ti)
{
    if (blockIdx.x >= NLSA) {
        long idx = (long)(blockIdx.x - NLSA) * 256 + threadIdx.x;
        if (idx >= (long)BS * NQ * NTOT) return;
        int t = (int)(idx % NTOT);
        int p = (int)(idx / NTOT);
        C[idx] = cost_element(logits, pboxes, labels, tboxes, p, t);
        return;
    }

    // ---- LSA block ----
    const int blk = blockIdx.x;          // 0..175
    const int b = blk / GN, g = blk % GN;
    const int tid = threadIdx.x;

    __shared__ double lcost[NROW * MCOL];   // [row i][col j]

    // All 256 threads fill the 48x50 tile, then waves 1-3 exit.
    for (int k = tid; k < NROW * MCOL; k += 256) {
        int i = k % NROW, j = k / NROW;
        float cf = cost_element(logits, pboxes, labels, tboxes,
                                b * NQ + g * GQ + j, b * NT + i);
        lcost[i * MCOL + j] = (double)cf;
    }
    __syncthreads();
    if (tid >= 64) return;

    const int lane = tid;
    const bool incol = (lane >= 1 && lane <= MCOL);
    const int cidx = incol ? lane - 1 : 0;
    const double INF = __builtin_inf();
    const float INFF = __builtin_inff();

    int    pcol_l = 0;    // p[lane]   (0 = unassigned)
    double urow_l = 0.0;  // u[p[lane]]
    double v_l    = 0.0;  // v[lane]
    int    way_l  = 0;
    double minv_l = INF;
    float  kprev  = INFF; // f32 image of minv_l (monotone)
    bool   used_l = false;

    for (int i = 1; i <= NROW; ++i) {
        if (lane == 0) { pcol_l = i; urow_l = 0.0; }  // p[0]=i, u[i]=0
        minv_l = INF;
        kprev  = INFF;
        used_l = false;
        int j0 = 0;
        int i0 = i;            // p[j0], wave-uniform
        double u_i0 = 0.0;     // u[i0]
        double cd = lcost[(i0 - 1) * MCOL + cidx];   // pre-issued row load

        for (int guard = 0; guard <= MCOL + 1; ++guard) {
            used_l = used_l || (lane == j0);
            bool freel = incol && !used_l;

            double cur = (cd - u_i0) - v_l;           // (cost - u) - v, ref order
            bool upd   = freel && (cur < minv_l);
            minv_l = upd ? cur : minv_l;
            way_l  = upd ? j0  : way_l;

            // f32 key: exact image of updated minv for free lanes, +inf else
            // (fminf(cvt(cur), kprev) == cvt(min(cur, minv_old)) by monotonicity)
            float kf = freel ? fminf(__double2float_rn(cur), kprev) : INFF;

            // argmin via u32 key: 4 within-row DPP stages -> row minima at
            // lanes 15/31/47/63 -> readlane x4 -> SALU min tree -> ballot.
            unsigned ukey = fkey_u32(kf);
            unsigned red = ukey;
            red = dpp_min_u32<0x111>(red);  // row_shr:1
            red = dpp_min_u32<0x112>(red);  // row_shr:2
            red = dpp_min_u32<0x114>(red);  // row_shr:4
            red = dpp_min_u32<0x118>(red);  // row_shr:8
            unsigned m0 = (unsigned)__builtin_amdgcn_readlane((int)red, 15);
            unsigned m1 = (unsigned)__builtin_amdgcn_readlane((int)red, 31);
            unsigned m2 = (unsigned)__builtin_amdgcn_readlane((int)red, 47);
            unsigned m3 = (unsigned)__builtin_amdgcn_readlane((int)red, 63);
            unsigned ka = (m0 < m1) ? m0 : m1;
            unsigned kb = (m2 < m3) ? m2 : m3;
            unsigned kmin = (ka < kb) ? ka : kb;

            unsigned long long mm = __ballot(ukey == kmin);
            int j1 = (int)__builtin_ctzll(mm);        // lowest lane = np.argmin

            int    i0n   = __builtin_amdgcn_readlane(pcol_l, j1);
            double delta = readlane_f64(minv_l, j1);  // exact f64 min value
            double u_nx  = readlane_f64(urow_l, j1);

            // speculative next-row load issued before the f64 updates; row
            // clamped so the read is always in-bounds (result unused on break).
            int r_next = (i0n > 0) ? (i0n - 1) : 0;
            double cd_next = lcost[r_next * MCOL + cidx];

            urow_l = used_l ? urow_l + delta : urow_l;
            v_l    = used_l ? v_l - delta    : v_l;
            minv_l = freel  ? minv_l - delta : minv_l;
            kprev  = __double2float_rn(minv_l);

            j0 = j1;
            if (i0n == 0) break;
            i0   = i0n;
            u_i0 = u_nx;
            cd   = cd_next;
        }

        // augment back-walk: p[j]=p[way[j]], moving urow with pcol
        int j = j0;
        while (j != 0) {
            int wj    = __builtin_amdgcn_readlane(way_l, j);
            int pr    = __builtin_amdgcn_readlane(pcol_l, wj);
            double ur = readlane_f64(urow_l, wj);
            if (lane == j) { pcol_l = pr; urow_l = ur; }
            j = wj;
        }
    }

    // Extraction: ascending query (column) order == reference order.
    unsigned long long asg = __ballot(incol && pcol_l != 0);
    if (incol && pcol_l != 0) {
        int k = __popcll(asg & ((1ull << lane) - 1));
        float* pib = pi + ((long)b * NPAIR + (long)g * NT);
        float* tib = ti + ((long)b * NPAIR + (long)g * NT);
        pib[k] = (float)(g * GQ + cidx);
        tib[k] = (float)(pcol_l - 1);
    }
}

extern "C" void kernel_launch(void* const* d_in, const int* in_sizes, int n_in,
                              void* d_out, int out_size, void* d_ws, size_t ws_size,
                              hipStream_t stream) {
    const float* logits = (const float*)d_in[0];   // [16,550,91] f32
    const float* pboxes = (const float*)d_in[1];   // [16,550,6] f32
    const int*   labels = (const int*)d_in[2];     // [16,48] i32
    const float* tboxes = (const float*)d_in[3];   // [16,48,6] f32

    float* out = (float*)d_out;
    float* C  = out;                               // 16*550*768
    float* pi = out + (long)BS * NQ * NTOT;
    float* ti = pi + (long)BS * NPAIR;

    long total = (long)BS * NQ * NTOT;
    int cost_blocks = (int)((total + 255) / 256);
    int mega_blocks = NLSA + cost_blocks;

    mega_kernel<<<mega_blocks, 256, 0, stream>>>(
        logits, pboxes, labels, tboxes, C, pi, ti);
}